// Round 5
// baseline (213.746 us; speedup 1.0000x reference)
//
#include <hip/hip_runtime.h>

#define T_ROWS    1048576
#define F_COLS    64
#define K_FEATS   16
#define WINDOW    128
#define C_ROWS    1024
#define NTHR      1024
#define F4        16                  // float4 per row
#define HALO      128
#define TOT_ROWS  (C_ROWS + HALO)     // 1152
#define NCHUNK    (TOT_ROWS / 16)     // 72 chunks of 16 rows
#define NSUB      64                  // row sub-groups in phase A
#define RPT       (C_ROWS / NSUB)     // 16 rows per phase-A thread
#define NBLK      (T_ROWS / C_ROWS)   // 1024
#define NXCD      8
#define CPX       (NBLK / NXCD)       // 128 blocks per XCD chunk

typedef float f32x4 __attribute__((ext_vector_type(4)));

__global__ __launch_bounds__(NTHR, 8) void ma_single_read_kernel(
    const float* __restrict__ inp,
    const int*   __restrict__ feats,
    float*       __restrict__ out)
{
    __shared__ float s_cols[TOT_ROWS][K_FEATS];   // 72 KB (no pad: keep 2 blocks/CU)
    __shared__ float s_ps[NCHUNK][K_FEATS];       // 4.5 KB

    const int tid = threadIdx.x;

    // T1: XCD-aware bijective swizzle (1024 % 8 == 0).
    const int bid     = blockIdx.x;
    const int logical = (bid & (NXCD - 1)) * CPX + (bid >> 3);
    const int r0      = logical * C_ROWS;
    const bool first  = (logical == 0);

    const float4* __restrict__ in4 = reinterpret_cast<const float4*>(inp);
    const long base = (long)r0 * F4;

    // ---- issue ALL global loads first ----
    float4 f[16];                                  // block's own 1024 rows
    #pragma unroll
    for (int j = 0; j < 16; ++j)
        f[j] = in4[base + tid + j * NTHR];

    float4 h[2];                                   // 128 halo rows
    if (!first) {
        const long hbase = (long)(r0 - HALO) * F4;
        #pragma unroll
        for (int m = 0; m < 2; ++m)
            h[m] = in4[hbase + tid + m * NTHR];
    }

    // ---- per-thread feat mapping: this thread always owns cols c0..c0+3 ----
    // (tid + j*1024) & 15 == tid & 15, so the float4 slot is thread-invariant.
    const int c0 = (tid & 15) * 4;
    int k0 = -1, k1 = -1, k2 = -1, k3 = -1;
    #pragma unroll
    for (int i = 0; i < K_FEATS; ++i) {
        const int c = feats[i];                    // uniform -> scalar loads
        if (c == c0 + 0) k0 = i;
        if (c == c0 + 1) k1 = i;
        if (c == c0 + 2) k2 = i;
        if (c == c0 + 3) k3 = i;
    }
    const int rb = tid >> 4;                       // row-base 0..63

    // ---- extraction: scatter feat columns into s_cols ----
    if (!first) {
        #pragma unroll
        for (int m = 0; m < 2; ++m) {
            const int r = rb + m * 64;             // halo rows 0..127
            if (k0 >= 0) s_cols[r][k0] = h[m].x;
            if (k1 >= 0) s_cols[r][k1] = h[m].y;
            if (k2 >= 0) s_cols[r][k2] = h[m].z;
            if (k3 >= 0) s_cols[r][k3] = h[m].w;
        }
    } else {
        if (tid < HALO) {
            #pragma unroll
            for (int k = 0; k < K_FEATS; ++k) s_cols[tid][k] = 0.0f;
        }
    }
    #pragma unroll
    for (int j = 0; j < 16; ++j) {
        const int r = HALO + rb + j * 64;          // own rows 128..1151
        if (k0 >= 0) s_cols[r][k0] = f[j].x;
        if (k1 >= 0) s_cols[r][k1] = f[j].y;
        if (k2 >= 0) s_cols[r][k2] = f[j].z;
        if (k3 >= 0) s_cols[r][k3] = f[j].w;
    }
    __syncthreads();

    // ---- stage 1: 16-row chunk sums ----
    {
        const int k  = tid & 15;
        const int cA = tid >> 4;                   // 0..63
        float s = 0.0f;
        #pragma unroll
        for (int i = 0; i < 16; ++i) s += s_cols[cA * 16 + i][k];
        s_ps[cA][k] = s;
        if (cA < NCHUNK - 64) {                    // chunks 64..71
            const int cB = cA + 64;
            float s2 = 0.0f;
            #pragma unroll
            for (int i = 0; i < 16; ++i) s2 += s_cols[cB * 16 + i][k];
            s_ps[cB][k] = s2;
        }
    }
    __syncthreads();

    // ---- stage 2: warmup from 8 chunk sums, then 16-step slide ----
    float means[RPT];
    const int k   = tid & 15;
    const int sub = tid >> 4;                      // 0..63
    {
        float S = 0.0f;
        #pragma unroll
        for (int m = 0; m < 8; ++m) S += s_ps[sub + m][k];
        const float inv = 1.0f / (float)WINDOW;
        #pragma unroll
        for (int i = 0; i < RPT; ++i) {
            means[i] = S * inv;
            S += s_cols[HALO + sub * RPT + i][k] - s_cols[sub * RPT + i][k];
        }
    }
    __syncthreads();
    #pragma unroll
    for (int i = 0; i < RPT; ++i)
        s_cols[HALO + sub * RPT + i][k] = means[i]; // means in place
    __syncthreads();

    // ---- substitution + coalesced NT store from registers ----
    f32x4* __restrict__ out4 = reinterpret_cast<f32x4*>(out);
    if (!first) {
        #pragma unroll
        for (int j = 0; j < 16; ++j) {
            const int r = rb + j * 64;
            if (k0 >= 0) f[j].x = s_cols[HALO + r][k0];
            if (k1 >= 0) f[j].y = s_cols[HALO + r][k1];
            if (k2 >= 0) f[j].z = s_cols[HALO + r][k2];
            if (k3 >= 0) f[j].w = s_cols[HALO + r][k3];
            f32x4 v = { f[j].x, f[j].y, f[j].z, f[j].w };
            __builtin_nontemporal_store(v, &out4[base + tid + j * NTHR]);
        }
    } else {
        #pragma unroll
        for (int j = 0; j < 16; ++j) {
            const int r = rb + j * 64;
            if (j >= 2) {                          // r >= 128 iff j >= 2
                if (k0 >= 0) f[j].x = s_cols[HALO + r][k0];
                if (k1 >= 0) f[j].y = s_cols[HALO + r][k1];
                if (k2 >= 0) f[j].z = s_cols[HALO + r][k2];
                if (k3 >= 0) f[j].w = s_cols[HALO + r][k3];
            }
            f32x4 v = { f[j].x, f[j].y, f[j].z, f[j].w };
            __builtin_nontemporal_store(v, &out4[base + tid + j * NTHR]);
        }
    }
}

extern "C" void kernel_launch(void* const* d_in, const int* in_sizes, int n_in,
                              void* d_out, int out_size, void* d_ws, size_t ws_size,
                              hipStream_t stream) {
    const float* inp   = (const float*)d_in[0];
    const int*   feats = (const int*)d_in[1];
    float*       out   = (float*)d_out;

    dim3 grid(NBLK);   // 1024 blocks
    dim3 block(NTHR);
    hipLaunchKernelGGL(ma_single_read_kernel, grid, block, 0, stream,
                       inp, feats, out);
}

// Round 6
// 146.787 us; speedup vs baseline: 1.4562x; 1.4562x over previous
//
#include <hip/hip_runtime.h>

#define T_ROWS    1048576
#define F_COLS    64
#define K_FEATS   16
#define WINDOW    128
#define C_ROWS    512
#define NTHR      512
#define F4        16                  // float4 per row
#define HALO      128
#define TOT_ROWS  (C_ROWS + HALO)     // 640
#define SPAD      17                  // padded leading dim for s_cols
#define NCHUNK    (TOT_ROWS / 16)     // 40 chunks of 16 rows
#define NSUB      32                  // row sub-groups in phase A
#define RPT       (C_ROWS / NSUB)     // 16 rows per phase-A thread
#define NBLK      (T_ROWS / C_ROWS)   // 2048
#define NXCD      8
#define CPX       (NBLK / NXCD)       // 256 blocks per XCD chunk

typedef float f32x4 __attribute__((ext_vector_type(4)));

__global__ __launch_bounds__(NTHR, 4) void ma_single_read_kernel(
    const float* __restrict__ inp,
    const int*   __restrict__ feats,
    float*       __restrict__ out)
{
    __shared__ float s_cols[TOT_ROWS][SPAD];   // 43.5 KB
    __shared__ float s_ps[NCHUNK][K_FEATS];    // 2.5 KB

    const int tid = threadIdx.x;

    // T1: XCD-aware bijective swizzle (2048 % 8 == 0).
    const int bid     = blockIdx.x;
    const int logical = (bid & (NXCD - 1)) * CPX + (bid >> 3);
    const int r0      = logical * C_ROWS;
    const bool first  = (logical == 0);

    const float4* __restrict__ in4  = reinterpret_cast<const float4*>(inp);
    f32x4*        __restrict__ out4 = reinterpret_cast<f32x4*>(out);
    const long base = (long)r0 * F4;

    // ---- per-thread feat mapping first (scalar loads, independent) ----
    // (tid + j*512) & 15 == tid & 15, so the float4 slot is thread-invariant.
    const int c0 = (tid & 15) * 4;
    int k0 = -1, k1 = -1, k2 = -1, k3 = -1;
    #pragma unroll
    for (int i = 0; i < K_FEATS; ++i) {
        const int c = feats[i];                    // uniform -> scalar loads
        if (c == c0 + 0) k0 = i;
        if (c == c0 + 1) k1 = i;
        if (c == c0 + 2) k2 = i;
        if (c == c0 + 3) k3 = i;
    }
    const bool clean = (k0 < 0) & (k1 < 0) & (k2 < 0) & (k3 < 0);
    const int rb = tid >> 4;                       // row-base 0..31

    // ---- issue ALL global loads ----
    float4 f[16];                                  // block's own 512 rows
    #pragma unroll
    for (int j = 0; j < 16; ++j)
        f[j] = in4[base + tid + j * NTHR];

    float4 h[4];                                   // 128 halo rows
    if (!first) {
        const long hbase = (long)(r0 - HALO) * F4;
        #pragma unroll
        for (int m = 0; m < 4; ++m)
            h[m] = in4[hbase + tid + m * NTHR];
    }

    // ---- EARLY STORE: threads whose slot holds no feat column write now ----
    // Pulls ~31% of the write stream into the read window (phase overlap).
    if (clean) {
        #pragma unroll
        for (int j = 0; j < 16; ++j) {
            f32x4 v = { f[j].x, f[j].y, f[j].z, f[j].w };
            __builtin_nontemporal_store(v, &out4[base + tid + j * NTHR]);
        }
    }

    // ---- extraction: scatter feat columns into s_cols (clean threads no-op) ----
    if (!first) {
        #pragma unroll
        for (int m = 0; m < 4; ++m) {
            const int r = rb + m * 32;             // halo rows 0..127
            if (k0 >= 0) s_cols[r][k0] = h[m].x;
            if (k1 >= 0) s_cols[r][k1] = h[m].y;
            if (k2 >= 0) s_cols[r][k2] = h[m].z;
            if (k3 >= 0) s_cols[r][k3] = h[m].w;
        }
    } else {
        if (tid < HALO) {
            #pragma unroll
            for (int k = 0; k < K_FEATS; ++k) s_cols[tid][k] = 0.0f;
        }
    }
    #pragma unroll
    for (int j = 0; j < 16; ++j) {
        const int r = HALO + rb + j * 32;          // own rows 128..639
        if (k0 >= 0) s_cols[r][k0] = f[j].x;
        if (k1 >= 0) s_cols[r][k1] = f[j].y;
        if (k2 >= 0) s_cols[r][k2] = f[j].z;
        if (k3 >= 0) s_cols[r][k3] = f[j].w;
    }
    __syncthreads();

    // ---- stage 1: 16-row chunk sums ----
    {
        const int k  = tid & 15;
        const int cA = tid >> 4;                   // 0..31
        float s = 0.0f;
        #pragma unroll
        for (int i = 0; i < 16; ++i) s += s_cols[cA * 16 + i][k];
        s_ps[cA][k] = s;
        if (cA < NCHUNK - 32) {                    // chunks 32..39
            const int cB = cA + 32;
            float s2 = 0.0f;
            #pragma unroll
            for (int i = 0; i < 16; ++i) s2 += s_cols[cB * 16 + i][k];
            s_ps[cB][k] = s2;
        }
    }
    __syncthreads();

    // ---- stage 2: warmup from 8 chunk sums, then 16-step slide ----
    float means[RPT];
    const int k   = tid & 15;
    const int sub = tid >> 4;                      // 0..31
    {
        float S = 0.0f;
        #pragma unroll
        for (int m = 0; m < 8; ++m) S += s_ps[sub + m][k];
        const float inv = 1.0f / (float)WINDOW;
        #pragma unroll
        for (int i = 0; i < RPT; ++i) {
            means[i] = S * inv;
            S += s_cols[HALO + sub * RPT + i][k] - s_cols[sub * RPT + i][k];
        }
    }
    __syncthreads();
    #pragma unroll
    for (int i = 0; i < RPT; ++i)
        s_cols[HALO + sub * RPT + i][k] = means[i]; // means in place
    __syncthreads();

    // ---- LATE STORE: dirty threads substitute means, then store ----
    if (!clean) {
        if (!first) {
            #pragma unroll
            for (int j = 0; j < 16; ++j) {
                const int r = rb + j * 32;
                if (k0 >= 0) f[j].x = s_cols[HALO + r][k0];
                if (k1 >= 0) f[j].y = s_cols[HALO + r][k1];
                if (k2 >= 0) f[j].z = s_cols[HALO + r][k2];
                if (k3 >= 0) f[j].w = s_cols[HALO + r][k3];
                f32x4 v = { f[j].x, f[j].y, f[j].z, f[j].w };
                __builtin_nontemporal_store(v, &out4[base + tid + j * NTHR]);
            }
        } else {
            #pragma unroll
            for (int j = 0; j < 16; ++j) {
                const int r = rb + j * 32;
                if (j >= 4) {                      // r >= 128 iff j >= 4
                    if (k0 >= 0) f[j].x = s_cols[HALO + r][k0];
                    if (k1 >= 0) f[j].y = s_cols[HALO + r][k1];
                    if (k2 >= 0) f[j].z = s_cols[HALO + r][k2];
                    if (k3 >= 0) f[j].w = s_cols[HALO + r][k3];
                }
                f32x4 v = { f[j].x, f[j].y, f[j].z, f[j].w };
                __builtin_nontemporal_store(v, &out4[base + tid + j * NTHR]);
            }
        }
    }
}

extern "C" void kernel_launch(void* const* d_in, const int* in_sizes, int n_in,
                              void* d_out, int out_size, void* d_ws, size_t ws_size,
                              hipStream_t stream) {
    const float* inp   = (const float*)d_in[0];
    const int*   feats = (const int*)d_in[1];
    float*       out   = (float*)d_out;

    dim3 grid(NBLK);   // 2048 blocks
    dim3 block(NTHR);
    hipLaunchKernelGGL(ma_single_read_kernel, grid, block, 0, stream,
                       inp, feats, out);
}

// Round 7
// 128.150 us; speedup vs baseline: 1.6679x; 1.1454x over previous
//
#include <hip/hip_runtime.h>

#define T_ROWS    1048576
#define F_COLS    64
#define K_FEATS   16
#define WINDOW    128
#define C_ROWS    256
#define NTHR      256
#define F4        16                  // float4 per row
#define HALO      128
#define TOT_ROWS  (C_ROWS + HALO)     // 384
#define SPAD      17                  // padded leading dim for s_cols
#define NCHUNK    (TOT_ROWS / 16)     // 24 chunks of 16 rows
#define NSUB      16                  // row sub-groups in phase A
#define RPT       (C_ROWS / NSUB)     // 16 rows per phase-A thread
#define NBLK      (T_ROWS / C_ROWS)   // 4096
#define NXCD      8
#define CPX       (NBLK / NXCD)       // 512 blocks per XCD chunk

typedef float f32x4 __attribute__((ext_vector_type(4)));

__global__ __launch_bounds__(NTHR, 5) void ma_single_read_kernel(
    const float* __restrict__ inp,
    const int*   __restrict__ feats,
    float*       __restrict__ out)
{
    __shared__ float s_cols[TOT_ROWS][SPAD];   // 26.1 KB
    __shared__ float s_ps[NCHUNK][K_FEATS];    // 1.5 KB

    const int tid = threadIdx.x;

    // T1: XCD-aware bijective swizzle (4096 % 8 == 0). Consecutive logical
    // tiles share an XCD -> halo reads hit the producer's L2.
    const int bid     = blockIdx.x;
    const int logical = (bid & (NXCD - 1)) * CPX + (bid >> 3);
    const int r0      = logical * C_ROWS;
    const bool first  = (logical == 0);

    const float4* __restrict__ in4  = reinterpret_cast<const float4*>(inp);
    f32x4*        __restrict__ out4 = reinterpret_cast<f32x4*>(out);
    const long base = (long)r0 * F4;

    // ---- per-thread feat mapping (scalar loads, issued first) ----
    // (tid + j*256) & 15 == tid & 15, so the float4 slot is thread-invariant.
    const int c0 = (tid & 15) * 4;
    int k0 = -1, k1 = -1, k2 = -1, k3 = -1;
    #pragma unroll
    for (int i = 0; i < K_FEATS; ++i) {
        const int c = feats[i];                    // uniform -> scalar loads
        if (c == c0 + 0) k0 = i;
        if (c == c0 + 1) k1 = i;
        if (c == c0 + 2) k2 = i;
        if (c == c0 + 3) k3 = i;
    }
    const int rb = tid >> 4;                       // row-base 0..15

    // ---- issue ALL global loads ----
    float4 f[16];                                  // block's own 256 rows
    #pragma unroll
    for (int j = 0; j < 16; ++j)
        f[j] = in4[base + tid + j * NTHR];

    float4 h[8];                                   // 128 halo rows
    if (!first) {
        const long hbase = (long)(r0 - HALO) * F4;
        #pragma unroll
        for (int m = 0; m < 8; ++m)
            h[m] = in4[hbase + tid + m * NTHR];
    }

    // ---- extraction: scatter feat columns into s_cols ----
    if (!first) {
        #pragma unroll
        for (int m = 0; m < 8; ++m) {
            const int r = rb + m * 16;             // halo rows 0..127
            if (k0 >= 0) s_cols[r][k0] = h[m].x;
            if (k1 >= 0) s_cols[r][k1] = h[m].y;
            if (k2 >= 0) s_cols[r][k2] = h[m].z;
            if (k3 >= 0) s_cols[r][k3] = h[m].w;
        }
    } else {
        if (tid < HALO) {
            #pragma unroll
            for (int k = 0; k < K_FEATS; ++k) s_cols[tid][k] = 0.0f;
        }
    }
    #pragma unroll
    for (int j = 0; j < 16; ++j) {
        const int r = HALO + rb + j * 16;          // own rows 128..383
        if (k0 >= 0) s_cols[r][k0] = f[j].x;
        if (k1 >= 0) s_cols[r][k1] = f[j].y;
        if (k2 >= 0) s_cols[r][k2] = f[j].z;
        if (k3 >= 0) s_cols[r][k3] = f[j].w;
    }
    __syncthreads();

    // ---- stage 1: 16-row chunk sums ----
    {
        const int k  = tid & 15;
        const int cA = tid >> 4;                   // 0..15
        float s = 0.0f;
        #pragma unroll
        for (int i = 0; i < 16; ++i) s += s_cols[cA * 16 + i][k];
        s_ps[cA][k] = s;
        if (cA < NCHUNK - 16) {                    // chunks 16..23
            const int cB = cA + 16;
            float s2 = 0.0f;
            #pragma unroll
            for (int i = 0; i < 16; ++i) s2 += s_cols[cB * 16 + i][k];
            s_ps[cB][k] = s2;
        }
    }
    __syncthreads();

    // ---- stage 2: warmup from 8 chunk sums, then 16-step slide ----
    float means[RPT];
    const int k   = tid & 15;
    const int sub = tid >> 4;                      // 0..15
    {
        float S = 0.0f;
        #pragma unroll
        for (int m = 0; m < 8; ++m) S += s_ps[sub + m][k];
        const float inv = 1.0f / (float)WINDOW;
        #pragma unroll
        for (int i = 0; i < RPT; ++i) {
            means[i] = S * inv;
            S += s_cols[HALO + sub * RPT + i][k] - s_cols[sub * RPT + i][k];
        }
    }
    __syncthreads();
    #pragma unroll
    for (int i = 0; i < RPT; ++i)
        s_cols[HALO + sub * RPT + i][k] = means[i]; // means in place
    __syncthreads();

    // ---- substitution + single full-line NT store per float4 ----
    if (!first) {
        #pragma unroll
        for (int j = 0; j < 16; ++j) {
            const int r = rb + j * 16;
            if (k0 >= 0) f[j].x = s_cols[HALO + r][k0];
            if (k1 >= 0) f[j].y = s_cols[HALO + r][k1];
            if (k2 >= 0) f[j].z = s_cols[HALO + r][k2];
            if (k3 >= 0) f[j].w = s_cols[HALO + r][k3];
            f32x4 v = { f[j].x, f[j].y, f[j].z, f[j].w };
            __builtin_nontemporal_store(v, &out4[base + tid + j * NTHR]);
        }
    } else {
        #pragma unroll
        for (int j = 0; j < 16; ++j) {
            const int r = rb + j * 16;
            if (j >= 8) {                          // r >= 128 iff j >= 8
                if (k0 >= 0) f[j].x = s_cols[HALO + r][k0];
                if (k1 >= 0) f[j].y = s_cols[HALO + r][k1];
                if (k2 >= 0) f[j].z = s_cols[HALO + r][k2];
                if (k3 >= 0) f[j].w = s_cols[HALO + r][k3];
            }
            f32x4 v = { f[j].x, f[j].y, f[j].z, f[j].w };
            __builtin_nontemporal_store(v, &out4[base + tid + j * NTHR]);
        }
    }
}

extern "C" void kernel_launch(void* const* d_in, const int* in_sizes, int n_in,
                              void* d_out, int out_size, void* d_ws, size_t ws_size,
                              hipStream_t stream) {
    const float* inp   = (const float*)d_in[0];
    const int*   feats = (const int*)d_in[1];
    float*       out   = (float*)d_out;

    dim3 grid(NBLK);   // 4096 blocks
    dim3 block(NTHR);
    hipLaunchKernelGGL(ma_single_read_kernel, grid, block, 0, stream,
                       inp, feats, out);
}

// Round 8
// 80.752 us; speedup vs baseline: 2.6470x; 1.5870x over previous
//
#include <hip/hip_runtime.h>

#define T_ROWS    1048576
#define F_COLS    64
#define K_FEATS   16
#define WINDOW    128
#define C_ROWS    512
#define NTHR      512
#define F4        16                  // float4 per row
#define HALO      128
#define TOT_ROWS  (C_ROWS + HALO)     // 640
#define SPAD      17                  // padded leading dim for s_cols
#define NCHUNK    (TOT_ROWS / 16)     // 40 chunks of 16 rows
#define NSUB      32                  // row sub-groups in phase A
#define RPT       (C_ROWS / NSUB)     // 16 rows per phase-A thread
#define NBLK      (T_ROWS / C_ROWS)   // 2048
#define NXCD      8
#define CPX       (NBLK / NXCD)       // 256 blocks per XCD chunk

typedef float f32x4 __attribute__((ext_vector_type(4)));

__global__ __launch_bounds__(NTHR, 4) void ma_single_read_kernel(
    const float* __restrict__ inp,
    const int*   __restrict__ feats,
    float*       __restrict__ out)
{
    __shared__ float s_cols[TOT_ROWS][SPAD];   // 43.5 KB
    __shared__ float s_ps[NCHUNK][K_FEATS];    // 2.5 KB

    const int tid = threadIdx.x;

    // T1: XCD-aware bijective swizzle (2048 % 8 == 0). Default dispatch
    // round-robins XCDs (bid%8 = XCD); remap so logically-consecutive row
    // chunks share an XCD -> halo reads hit that XCD's L2.
    const int bid     = blockIdx.x;
    const int logical = (bid & (NXCD - 1)) * CPX + (bid >> 3);
    const int r0      = logical * C_ROWS;
    const bool first  = (logical == 0);

    const float4* __restrict__ in4 = reinterpret_cast<const float4*>(inp);
    const long base = (long)r0 * F4;

    // ---- issue ALL global loads first (20 x 16B per thread in flight) ----
    float4 f[16];                                  // block's own 512 rows
    #pragma unroll
    for (int j = 0; j < 16; ++j)
        f[j] = in4[base + tid + j * NTHR];

    float4 h[4];                                   // 128 halo rows
    if (!first) {
        const long hbase = (long)(r0 - HALO) * F4;
        #pragma unroll
        for (int m = 0; m < 4; ++m)
            h[m] = in4[hbase + tid + m * NTHR];
    }

    // ---- per-thread feat mapping: this thread always owns cols c0..c0+3 ----
    const int c0 = (tid & 15) * 4;
    int k0 = -1, k1 = -1, k2 = -1, k3 = -1;
    #pragma unroll
    for (int i = 0; i < K_FEATS; ++i) {
        const int c = feats[i];                    // uniform -> scalar loads
        if (c == c0 + 0) k0 = i;
        if (c == c0 + 1) k1 = i;
        if (c == c0 + 2) k2 = i;
        if (c == c0 + 3) k3 = i;
    }
    const int rb = tid >> 4;                       // row-base 0..31

    // ---- extraction: scatter feat columns into s_cols ----
    if (!first) {
        #pragma unroll
        for (int m = 0; m < 4; ++m) {
            const int r = rb + m * 32;             // halo rows 0..127
            if (k0 >= 0) s_cols[r][k0] = h[m].x;
            if (k1 >= 0) s_cols[r][k1] = h[m].y;
            if (k2 >= 0) s_cols[r][k2] = h[m].z;
            if (k3 >= 0) s_cols[r][k3] = h[m].w;
        }
    } else {
        if (tid < HALO) {
            #pragma unroll
            for (int k = 0; k < K_FEATS; ++k) s_cols[tid][k] = 0.0f;
        }
    }
    #pragma unroll
    for (int j = 0; j < 16; ++j) {
        const int r = HALO + rb + j * 32;          // own rows 128..639
        if (k0 >= 0) s_cols[r][k0] = f[j].x;
        if (k1 >= 0) s_cols[r][k1] = f[j].y;
        if (k2 >= 0) s_cols[r][k2] = f[j].z;
        if (k3 >= 0) s_cols[r][k3] = f[j].w;
    }
    __syncthreads();

    // ---- stage 1: 16-row chunk sums ----
    {
        const int k  = tid & 15;
        const int cA = tid >> 4;                   // 0..31
        float s = 0.0f;
        #pragma unroll
        for (int i = 0; i < 16; ++i) s += s_cols[cA * 16 + i][k];
        s_ps[cA][k] = s;
        if (cA < NCHUNK - 32) {                    // chunks 32..39
            const int cB = cA + 32;
            float s2 = 0.0f;
            #pragma unroll
            for (int i = 0; i < 16; ++i) s2 += s_cols[cB * 16 + i][k];
            s_ps[cB][k] = s2;
        }
    }
    __syncthreads();

    // ---- stage 2: warmup from 8 chunk sums, then 16-step slide ----
    float means[RPT];
    const int k   = tid & 15;
    const int sub = tid >> 4;                      // 0..31
    {
        float S = 0.0f;
        #pragma unroll
        for (int m = 0; m < 8; ++m) S += s_ps[sub + m][k];
        const float inv = 1.0f / (float)WINDOW;
        #pragma unroll
        for (int i = 0; i < RPT; ++i) {
            means[i] = S * inv;
            S += s_cols[HALO + sub * RPT + i][k] - s_cols[sub * RPT + i][k];
        }
    }
    __syncthreads();
    #pragma unroll
    for (int i = 0; i < RPT; ++i)
        s_cols[HALO + sub * RPT + i][k] = means[i]; // means in place
    __syncthreads();

    // ---- substitution + coalesced NT store from registers ----
    f32x4* __restrict__ out4 = reinterpret_cast<f32x4*>(out);
    if (!first) {
        #pragma unroll
        for (int j = 0; j < 16; ++j) {
            const int r = rb + j * 32;
            if (k0 >= 0) f[j].x = s_cols[HALO + r][k0];
            if (k1 >= 0) f[j].y = s_cols[HALO + r][k1];
            if (k2 >= 0) f[j].z = s_cols[HALO + r][k2];
            if (k3 >= 0) f[j].w = s_cols[HALO + r][k3];
            f32x4 v = { f[j].x, f[j].y, f[j].z, f[j].w };
            __builtin_nontemporal_store(v, &out4[base + tid + j * NTHR]);
        }
    } else {
        #pragma unroll
        for (int j = 0; j < 16; ++j) {
            const int r = rb + j * 32;
            if (j >= 4) {                          // r >= 128 iff j >= 4
                if (k0 >= 0) f[j].x = s_cols[HALO + r][k0];
                if (k1 >= 0) f[j].y = s_cols[HALO + r][k1];
                if (k2 >= 0) f[j].z = s_cols[HALO + r][k2];
                if (k3 >= 0) f[j].w = s_cols[HALO + r][k3];
            }
            f32x4 v = { f[j].x, f[j].y, f[j].z, f[j].w };
            __builtin_nontemporal_store(v, &out4[base + tid + j * NTHR]);
        }
    }
}

extern "C" void kernel_launch(void* const* d_in, const int* in_sizes, int n_in,
                              void* d_out, int out_size, void* d_ws, size_t ws_size,
                              hipStream_t stream) {
    const float* inp   = (const float*)d_in[0];
    const int*   feats = (const int*)d_in[1];
    float*       out   = (float*)d_out;

    dim3 grid(NBLK);   // 2048 blocks
    dim3 block(NTHR);
    hipLaunchKernelGGL(ma_single_read_kernel, grid, block, 0, stream,
                       inp, feats, out);
}